// Round 3
// baseline (62.304 us; speedup 1.0000x reference)
//
#include <hip/hip_runtime.h>

// CRF NLL forward, B=8192, L=512, T=6 (4 real states + START/STOP).
// Pipeline:
//   sort:  hist -> scan -> scatter  => perm[] = batches ordered by seq_len
//   seg:   lane = (batch, segment, column). Each lane runs the 4-state scaled-
//          probability recurrence q <- diag(exp(feat))*E*q on ONE column of the
//          segment transfer matrix (columns are independent). Renorm by 2^-e
//          every 4 steps; per-column exponent accumulated in an int.
//          Segment 0: all 4 col-lanes compute the true alpha vector (init via
//          exp(trans[:,START]) at step 0); only col 0 stores. Gold path fused.
//   comb:  per batch, v <- P_s * v across segments with per-column exponent
//          reconciliation; finalize logZ - gold; reduce; atomicAdd.

#define BB 8192
#define LL 512
#define LN2F 0.69314718055994530942f

// -------------------- length-sort machinery --------------------
__global__ __launch_bounds__(256) void k_hist(const int* __restrict__ lens,
                                              int* __restrict__ hist) {
    const int b = blockIdx.x * 256 + threadIdx.x;
    atomicAdd(&hist[lens[b] - 1], 1);      // len in 1..512
}

__global__ __launch_bounds__(512) void k_scan(const int* __restrict__ hist,
                                              int* __restrict__ offs) {
    __shared__ int sh[512];
    const int t = threadIdx.x;
    const int own = hist[t];
    sh[t] = own;
    __syncthreads();
    for (int d = 1; d < 512; d <<= 1) {
        const int v = (t >= d) ? sh[t - d] : 0;
        __syncthreads();
        sh[t] += v;
        __syncthreads();
    }
    offs[t] = sh[t] - own;                 // exclusive prefix
}

__global__ __launch_bounds__(256) void k_scat(const int* __restrict__ lens,
                                              int* __restrict__ offs,
                                              int* __restrict__ perm) {
    const int b = blockIdx.x * 256 + threadIdx.x;
    const int pos = atomicAdd(&offs[lens[b] - 1], 1);
    perm[pos] = b;
}

// ---- load one 4-step chunk: 24 floats (6x float4) + 4 tags (int4) ----
#define LOADC(B0,B1,B2,B3,B4,B5,TG,C)                                   \
  do { if ((C) < NCH) {                                                 \
    const float4* p_ = (const float4*)(fb + (C)*24);                    \
    B0=p_[0]; B1=p_[1]; B2=p_[2]; B3=p_[3]; B4=p_[4]; B5=p_[5];         \
    TG = *(const int4*)(tb + (C)*4); } } while(0)

// one column step; E in SGPRs, renorm handled outside
#define CSTEP(FA,FB,FC,FD,TGV,LUTV,R)                                   \
  do {                                                                  \
    const bool act_ = (R) < act;                                        \
    const bool f0_  = seg0 && ((R) == 0);                               \
    const float fa_=(FA), fb2_=(FB), fc_=(FC), fd_=(FD);                \
    const float fe0_=__expf(fa_), fe1_=__expf(fb2_);                    \
    const float fe2_=__expf(fc_), fe3_=__expf(fd_);                     \
    float s0_ = fmaf(E[0],q0, fmaf(E[1],q1, fmaf(E[2],q2, E[3]*q3)));   \
    float s1_ = fmaf(E[4],q0, fmaf(E[5],q1, fmaf(E[6],q2, E[7]*q3)));   \
    float s2_ = fmaf(E[8],q0, fmaf(E[9],q1, fmaf(E[10],q2,E[11]*q3)));  \
    float s3_ = fmaf(E[12],q0,fmaf(E[13],q1,fmaf(E[14],q2,E[15]*q3)));  \
    s0_ = f0_ ? e4[0] : s0_;  s1_ = f0_ ? e4[1] : s1_;                  \
    s2_ = f0_ ? e4[2] : s2_;  s3_ = f0_ ? e4[3] : s3_;                  \
    q0 = act_ ? s0_*fe0_ : q0;  q1 = act_ ? s1_*fe1_ : q1;              \
    q2 = act_ ? s2_*fe2_ : q2;  q3 = act_ ? s3_*fe3_ : q3;              \
    const int tg_ = (TGV);                                              \
    const float fs_ = (tg_ & 2) ? ((tg_ & 1) ? fd_ : fc_)               \
                                : ((tg_ & 1) ? fb2_ : fa_);             \
    gold += act_ ? ((LUTV) + fs_) : 0.0f;                               \
    prev = act_ ? tg_ : prev;                                           \
  } while (0)

// renorm by exponent of max; exact power of 2 => safe unconditionally
#define CRENORM                                                         \
  do {                                                                  \
    const float cm_ = fmaxf(fmaxf(q0,q1), fmaxf(q2,q3));                \
    const int ee_ = (int)(__float_as_uint(cm_) >> 23) - 127;            \
    q0 = ldexpf(q0,-ee_); q1 = ldexpf(q1,-ee_);                         \
    q2 = ldexpf(q2,-ee_); q3 = ldexpf(q3,-ee_);                         \
    mex += ee_;                                                         \
  } while (0)

#define CPROC(B0,B1,B2,B3,B4,B5,TG,C)                                   \
  do {                                                                  \
    const int r0_ = (C) * 4;                                            \
    const int g0_ = (TG).x & 3, g1_ = (TG).y & 3;                       \
    const int g2_ = (TG).z & 3, g3_ = (TG).w & 3;                       \
    const float u0_ = sT[g0_*6 + prev];                                 \
    const float u1_ = sT[g1_*6 + g0_];                                  \
    const float u2_ = sT[g2_*6 + g1_];                                  \
    const float u3_ = sT[g3_*6 + g2_];                                  \
    CSTEP((B0).x,(B0).y,(B0).z,(B0).w, g0_, u0_, r0_+0);                \
    CSTEP((B1).z,(B1).w,(B2).x,(B2).y, g1_, u1_, r0_+1);                \
    CSTEP((B3).x,(B3).y,(B3).z,(B3).w, g2_, u2_, r0_+2);                \
    CSTEP((B4).z,(B4).w,(B5).x,(B5).y, g3_, u3_, r0_+3);                \
    CRENORM;                                                            \
  } while (0)

template<int S>
__global__ __launch_bounds__(256) void crf_seg(
    const float* __restrict__ feats,
    const float* __restrict__ trans,
    const int*   __restrict__ tags,
    const int*   __restrict__ lens,
    const int*   __restrict__ perm,
    float* __restrict__ mats,   // [S][16][B]   e = col*4 + row, indexed by p
    int*   __restrict__ mexs,   // [S][4][B]    per column
    float* __restrict__ golds)  // [S][B]
{
    constexpr int LSEG = LL / S;
    constexpr int NCH  = LSEG / 4;

    __shared__ float sT[36];   // raw transitions (gold LUT + terminal row)
    const int tid = threadIdx.x;
    if (tid < 36) sT[tid] = trans[tid];
    __syncthreads();

    // wave-uniform constants -> SGPRs
    float E[16], e4[4];
    #pragma unroll
    for (int i = 0; i < 16; ++i) {
        const float e = __expf(trans[(i >> 2) * 6 + (i & 3)]);
        E[i] = __uint_as_float(__builtin_amdgcn_readfirstlane(__float_as_uint(e)));
    }
    #pragma unroll
    for (int i = 0; i < 4; ++i) {
        const float e = __expf(trans[i * 6 + 4]);
        e4[i] = __uint_as_float(__builtin_amdgcn_readfirstlane(__float_as_uint(e)));
    }

    const int s    = blockIdx.x & (S - 1);
    const int grp  = blockIdx.x / S;
    const int slot = tid >> 2;
    const int col  = tid & 3;
    const int p    = grp * 64 + slot;     // sorted position
    const int b    = perm[p];             // actual batch
    const int len  = lens[b];
    const int s0   = s * LSEG;
    const int act  = min(len - s0, LSEG);
    const bool seg0 = (s == 0);
    const float* fb = feats + (size_t)b * (LL*6) + (size_t)s0 * 6;
    const int*   tb = tags  + (size_t)b * LL + s0;

    // column init: seg0 -> 0 (step 0 injects e4); else unit vector e_col
    float q0 = (!seg0 && col==0) ? 1.f : 0.f;
    float q1 = (!seg0 && col==1) ? 1.f : 0.f;
    float q2 = (!seg0 && col==2) ? 1.f : 0.f;
    float q3 = (!seg0 && col==3) ? 1.f : 0.f;
    int   mex  = 0;
    float gold = 0.f;
    int   prev = seg0 ? 4 : (tb[-1] & 3);

    const float4 z4 = make_float4(0.f,0.f,0.f,0.f);
    const int4   zi = make_int4(0,0,0,0);
    float4 a0=z4,a1=z4,a2=z4,a3=z4,a4=z4,a5=z4;
    float4 b0=z4,b1=z4,b2=z4,b3=z4,b4=z4,b5=z4;
    int4 at=zi, bt=zi;

    const int nch = (max(act, 0) + 3) >> 2;
    LOADC(a0,a1,a2,a3,a4,a5,at, 0);
    for (int c = 0; c < nch; c += 2) {
        LOADC(b0,b1,b2,b3,b4,b5,bt, c+1);
        CPROC(a0,a1,a2,a3,a4,a5,at, c);
        if (c + 1 >= nch) break;
        LOADC(a0,a1,a2,a3,a4,a5,at, c+2);
        CPROC(b0,b1,b2,b3,b4,b5,bt, c+1);
    }

    if (seg0) {
        if (col == 0) {
            mats[(size_t)0*BB + p] = q0;
            mats[(size_t)1*BB + p] = q1;
            mats[(size_t)2*BB + p] = q2;
            mats[(size_t)3*BB + p] = q3;
            mexs[(size_t)0*BB + p] = mex;
        }
    } else {
        const size_t eb = ((size_t)s*16 + col*4) * BB + p;
        mats[eb + 0*BB] = q0;
        mats[eb + 1*BB] = q1;
        mats[eb + 2*BB] = q2;
        mats[eb + 3*BB] = q3;
        mexs[((size_t)s*4 + col)*BB + p] = mex;
    }
    if (col == 0) {
        if (len > s0 && len <= s0 + LSEG)
            gold += sT[30 + (tb[len - 1 - s0] & 3)];   // trans[STOP][last]
        golds[(size_t)s*BB + p] = gold;
    }
}

template<int S>
__global__ __launch_bounds__(256) void crf_comb(
    const float* __restrict__ mats,
    const int*   __restrict__ mexs,
    const float* __restrict__ golds,
    const float* __restrict__ trans,
    const int*   __restrict__ lens,
    const int*   __restrict__ perm,
    float* __restrict__ out)
{
    constexpr int LSEG = LL / S;
    const int tid = threadIdx.x;
    const int p   = blockIdx.x * 256 + tid;
    const int len = lens[perm[p]];

    float v0 = mats[(size_t)0*BB + p], v1 = mats[(size_t)1*BB + p];
    float v2 = mats[(size_t)2*BB + p], v3 = mats[(size_t)3*BB + p];
    int   vex  = mexs[(size_t)0*BB + p];
    float gold = 0.f;
    #pragma unroll
    for (int s = 0; s < S; ++s) gold += golds[(size_t)s*BB + p];

    // wave-uniform exit bound (p is length-sorted => tight)
    int lmax = len;
    #pragma unroll
    for (int off = 32; off > 0; off >>= 1)
        lmax = max(lmax, __shfl_xor(lmax, off, 64));

    for (int s = 1; s < S; ++s) {
        if (s * LSEG >= lmax) break;
        const bool a = (s * LSEG) < len;
        float P[16]; int mc[4];
        #pragma unroll
        for (int e = 0; e < 16; ++e)
            P[e] = a ? mats[((size_t)s*16 + e)*BB + p] : 0.f;
        #pragma unroll
        for (int c = 0; c < 4; ++c)
            mc[c] = a ? mexs[((size_t)s*4 + c)*BB + p] : 0;
        const int mm = max(max(mc[0],mc[1]), max(mc[2],mc[3]));
        const float w0 = ldexpf(v0, mc[0]-mm), w1 = ldexpf(v1, mc[1]-mm);
        const float w2 = ldexpf(v2, mc[2]-mm), w3 = ldexpf(v3, mc[3]-mm);
        const float n0 = fmaf(P[0],w0, fmaf(P[4],w1, fmaf(P[8], w2, P[12]*w3)));
        const float n1 = fmaf(P[1],w0, fmaf(P[5],w1, fmaf(P[9], w2, P[13]*w3)));
        const float n2 = fmaf(P[2],w0, fmaf(P[6],w1, fmaf(P[10],w2, P[14]*w3)));
        const float n3 = fmaf(P[3],w0, fmaf(P[7],w1, fmaf(P[11],w2, P[15]*w3)));
        const float m_ = fmaxf(fmaxf(n0,n1), fmaxf(n2,n3));
        const int ee = (int)(__float_as_uint(m_) >> 23) - 127;
        if (a) {
            v0 = ldexpf(n0,-ee); v1 = ldexpf(n1,-ee);
            v2 = ldexpf(n2,-ee); v3 = ldexpf(n3,-ee);
            vex += mm + ee;
        }
    }

    const float e50=__expf(trans[30]), e51=__expf(trans[31]);
    const float e52=__expf(trans[32]), e53=__expf(trans[33]);
    const float dot = fmaf(e50,v0, fmaf(e51,v1, fmaf(e52,v2, e53*v3)));
    const float logz = fmaf((float)vex, LN2F, __logf(dot));
    float r = logz - gold;

    #pragma unroll
    for (int off = 32; off > 0; off >>= 1)
        r += __shfl_xor(r, off, 64);
    if ((tid & 63) == 0)
        atomicAdd(out, r * (1.0f / 8192.0f));
}

template<int S>
static void launch_all(const float* feats, const float* trans, const int* tags,
                       const int* lens, float* out, void* d_ws, hipStream_t stream) {
    float* mats  = (float*)d_ws;
    int*   mexs  = (int*)  (mats  + (size_t)S * 16 * BB);
    float* golds = (float*)(mexs  + (size_t)S * 4  * BB);
    int*   perm  = (int*)  (golds + (size_t)S * BB);
    int*   hist  = perm + BB;
    int*   offs  = hist + 512;

    hipMemsetAsync(hist, 0, 512 * sizeof(int), stream);
    k_hist<<<BB/256, 256, 0, stream>>>(lens, hist);
    k_scan<<<1, 512, 0, stream>>>(hist, offs);
    k_scat<<<BB/256, 256, 0, stream>>>(lens, offs, perm);
    crf_seg<S><<<(BB/64)*S, 256, 0, stream>>>(feats, trans, tags, lens, perm,
                                              mats, mexs, golds);
    crf_comb<S><<<BB/256, 256, 0, stream>>>(mats, mexs, golds, trans, lens,
                                            perm, out);
}

extern "C" void kernel_launch(void* const* d_in, const int* in_sizes, int n_in,
                              void* d_out, int out_size, void* d_ws, size_t ws_size,
                              hipStream_t stream) {
    const float* feats = (const float*)d_in[0];
    const float* trans = (const float*)d_in[1];
    const int*   tags  = (const int*)d_in[2];
    const int*   lens  = (const int*)d_in[3];
    float* out = (float*)d_out;

    auto need = [](int S) -> size_t {
        return (size_t)S*16*BB*4 + (size_t)S*4*BB*4 + (size_t)S*BB*4
             + (size_t)BB*4 + 1024*4;
    };
    int S = 16;
    while (S > 1 && need(S) > ws_size) S >>= 1;

    hipMemsetAsync(out, 0, sizeof(float) * out_size, stream);

    switch (S) {
      case 16: launch_all<16>(feats, trans, tags, lens, out, d_ws, stream); break;
      case 8:  launch_all<8> (feats, trans, tags, lens, out, d_ws, stream); break;
      case 4:  launch_all<4> (feats, trans, tags, lens, out, d_ws, stream); break;
      case 2:  launch_all<2> (feats, trans, tags, lens, out, d_ws, stream); break;
      default: launch_all<1> (feats, trans, tags, lens, out, d_ws, stream); break;
    }
}

// Round 4
// 59.242 us; speedup vs baseline: 1.0517x; 1.0517x over previous
//
#include <hip/hip_runtime.h>

// CRF NLL forward, B=8192, L=512, T=6 (4 real states + START/STOP).
//   k_sort: single block; hist+scan+scatter of seq_lengths -> perm (and zero out)
//   crf_seg<S>: lane = (sorted-pos, segment, column). 4-state scaled-prob
//     recurrence on one column of the segment transfer matrix. Feats/tags are
//     block-cooperatively staged into LDS (coalesced, full-line reads), async
//     split: next stage's global loads issued before current compute.
//   crf_comb<S>: per batch chain the segment matrices, finalize logz - gold.

#define BB 8192
#define LL 512
#define LN2F 0.69314718055994530942f

// ---------------- fused sort (single block) ----------------
__global__ __launch_bounds__(512) void k_sort(const int* __restrict__ lens,
                                              int* __restrict__ perm,
                                              float* __restrict__ out,
                                              int out_size) {
    __shared__ int hist[512];
    __shared__ int offs[512];
    const int t = threadIdx.x;
    if (t < out_size) out[t] = 0.0f;
    hist[t] = 0;
    __syncthreads();
    for (int i = t; i < BB; i += 512)
        atomicAdd(&hist[lens[i] - 1], 1);          // len in 1..512
    __syncthreads();
    const int own = hist[t];
    offs[t] = own;
    __syncthreads();
    for (int d = 1; d < 512; d <<= 1) {            // Hillis-Steele inclusive
        const int w = (t >= d) ? offs[t - d] : 0;
        __syncthreads();
        offs[t] += w;
        __syncthreads();
    }
    const int excl = offs[t] - own;
    __syncthreads();
    offs[t] = excl;                                 // running cursors
    __syncthreads();
    for (int i = t; i < BB; i += 512) {
        const int pos = atomicAdd(&offs[lens[i] - 1], 1);
        perm[pos] = i;
    }
}

// one column step; E/e4 wave-uniform, renorm outside
#define CSTEP(FA,FB,FC,FD,TGV,LUTV,R)                                   \
  do {                                                                  \
    const bool act_ = (R) < act;                                        \
    const bool f0_  = seg0 && ((R) == 0);                               \
    const float fa_=(FA), fb2_=(FB), fc_=(FC), fd_=(FD);                \
    const float fe0_=__expf(fa_), fe1_=__expf(fb2_);                    \
    const float fe2_=__expf(fc_), fe3_=__expf(fd_);                     \
    float s0_ = fmaf(E[0],q0, fmaf(E[1],q1, fmaf(E[2],q2, E[3]*q3)));   \
    float s1_ = fmaf(E[4],q0, fmaf(E[5],q1, fmaf(E[6],q2, E[7]*q3)));   \
    float s2_ = fmaf(E[8],q0, fmaf(E[9],q1, fmaf(E[10],q2,E[11]*q3)));  \
    float s3_ = fmaf(E[12],q0,fmaf(E[13],q1,fmaf(E[14],q2,E[15]*q3)));  \
    s0_ = f0_ ? e4[0] : s0_;  s1_ = f0_ ? e4[1] : s1_;                  \
    s2_ = f0_ ? e4[2] : s2_;  s3_ = f0_ ? e4[3] : s3_;                  \
    q0 = act_ ? s0_*fe0_ : q0;  q1 = act_ ? s1_*fe1_ : q1;              \
    q2 = act_ ? s2_*fe2_ : q2;  q3 = act_ ? s3_*fe3_ : q3;              \
    const int tg_ = (TGV);                                              \
    const float fs_ = (tg_ & 2) ? ((tg_ & 1) ? fd_ : fc_)               \
                                : ((tg_ & 1) ? fb2_ : fa_);             \
    gold += act_ ? ((LUTV) + fs_) : 0.0f;                               \
    prev = act_ ? tg_ : prev;                                           \
  } while (0)

#define CRENORM                                                         \
  do {                                                                  \
    const float cm_ = fmaxf(fmaxf(q0,q1), fmaxf(q2,q3));                \
    const int ee_ = (int)(__float_as_uint(cm_) >> 23) - 127;            \
    q0 = ldexpf(q0,-ee_); q1 = ldexpf(q1,-ee_);                         \
    q2 = ldexpf(q2,-ee_); q3 = ldexpf(q3,-ee_);                         \
    mex += ee_;                                                         \
  } while (0)

#define CPROC(B0,B1,B2,B3,B4,B5,TG,C)                                   \
  do {                                                                  \
    const int r0_ = (C) * 4;                                            \
    const int g0_ = (TG).x & 3, g1_ = (TG).y & 3;                       \
    const int g2_ = (TG).z & 3, g3_ = (TG).w & 3;                       \
    const float u0_ = sT[g0_*6 + prev];                                 \
    const float u1_ = sT[g1_*6 + g0_];                                  \
    const float u2_ = sT[g2_*6 + g1_];                                  \
    const float u3_ = sT[g3_*6 + g2_];                                  \
    CSTEP((B0).x,(B0).y,(B0).z,(B0).w, g0_, u0_, r0_+0);                \
    CSTEP((B1).z,(B1).w,(B2).x,(B2).y, g1_, u1_, r0_+1);                \
    CSTEP((B3).x,(B3).y,(B3).z,(B3).w, g2_, u2_, r0_+2);                \
    CSTEP((B4).z,(B4).w,(B5).x,(B5).y, g3_, u3_, r0_+3);                \
    CRENORM;                                                            \
  } while (0)

template<int S>
__global__ __launch_bounds__(256) void crf_seg(
    const float* __restrict__ feats,
    const float* __restrict__ trans,
    const int*   __restrict__ tags,
    const int*   __restrict__ lens,
    const int*   __restrict__ perm,
    float* __restrict__ mats,   // [S*16 + col*4 + row][BB], by sorted pos
    int*   __restrict__ mexs,   // [S*4 + col][BB]
    float* __restrict__ golds)  // [S][BB]
{
    constexpr int LSEG = LL / S;
    constexpr int NCH  = LSEG / 4;

    __shared__ float4 sF[780];   // [u<12][65] padded (2 chunks x 64 pos)
    __shared__ int4   sG[128];   // [w<2][64]
    __shared__ float  sT[36];
    __shared__ int    sB[64];    // batch id per pos
    __shared__ int    sL[64];    // len per pos
    __shared__ int    sMax;

    const int tid = threadIdx.x;
    const int s   = blockIdx.x & (S - 1);
    const int grp = blockIdx.x / S;
    const int P0  = grp * 64;
    const int s0  = s * LSEG;

    if (tid < 36) sT[tid] = trans[tid];
    if (tid < 64) {
        const int b = perm[P0 + tid];
        sB[tid] = b;
        sL[tid] = lens[b];
    }
    __syncthreads();
    if (tid < 64) {
        int l = sL[tid];
        #pragma unroll
        for (int off = 32; off > 0; off >>= 1)
            l = max(l, __shfl_xor(l, off, 64));
        if (tid == 0) sMax = l;
    }
    __syncthreads();
    const int maxact = min(sMax - s0, LSEG);
    if (maxact <= 0) return;            // block-uniform; comb never reads these
    const int maxnch = (maxact + 3) >> 2;
    const int NQ     = (maxnch + 1) >> 1;

    // wave-uniform transition constants
    float E[16], e4[4];
    #pragma unroll
    for (int i = 0; i < 16; ++i) {
        const float e = __expf(trans[(i >> 2) * 6 + (i & 3)]);
        E[i] = __uint_as_float(__builtin_amdgcn_readfirstlane(__float_as_uint(e)));
    }
    #pragma unroll
    for (int i = 0; i < 4; ++i) {
        const float e = __expf(trans[i * 6 + 4]);
        e4[i] = __uint_as_float(__builtin_amdgcn_readfirstlane(__float_as_uint(e)));
    }

    // ---- staging thread roles: 3 float4 slots + (tid<128) 1 tag int4 ----
    const float4* f4 = (const float4*)feats;
    const int4*   t4 = (const int4*)tags;
    const int i0 = tid, i1 = tid + 256, i2 = tid + 512;
    const int p0_ = i0 / 12, u0_ = i0 - p0_ * 12;
    const int p1_ = i1 / 12, u1_ = i1 - p1_ * 12;
    const int p2_ = i2 / 12, u2_ = i2 - p2_ * 12;
    const float4* src0 = f4 + (size_t)sB[p0_] * 768 + 48 * s + u0_;
    const float4* src1 = f4 + (size_t)sB[p1_] * 768 + 48 * s + u1_;
    const float4* src2 = f4 + (size_t)sB[p2_] * 768 + 48 * s + u2_;
    const int d0 = u0_ * 65 + p0_, d1 = u1_ * 65 + p1_, d2 = u2_ * 65 + p2_;
    const int pT = tid >> 1, wT = tid & 1;
    const int4* srcT = t4 + (size_t)sB[pT] * 128 + 8 * s + wT;
    const int dT = wT * 64 + pT;

    float4 r0, r1, r2; int4 rt;
#define SLOAD(Q)  do { r0 = src0[12*(Q)]; r1 = src1[12*(Q)];            \
                       r2 = src2[12*(Q)];                               \
                       if (tid < 128) rt = srcT[2*(Q)]; } while (0)
#define SWRITE()  do { sF[d0] = r0; sF[d1] = r1; sF[d2] = r2;           \
                       if (tid < 128) sG[dT] = rt; } while (0)

    // ---- compute lane state ----
    const int slot = tid >> 2;
    const int col  = tid & 3;
    const int p    = P0 + slot;
    const int b    = sB[slot];
    const int len  = sL[slot];
    const int act  = min(len - s0, LSEG);
    const bool seg0 = (s == 0);

    float q0 = (!seg0 && col==0) ? 1.f : 0.f;
    float q1 = (!seg0 && col==1) ? 1.f : 0.f;
    float q2 = (!seg0 && col==2) ? 1.f : 0.f;
    float q3 = (!seg0 && col==3) ? 1.f : 0.f;
    int   mex  = 0;
    float gold = 0.f;
    int   prev = seg0 ? 4 : (tags[(size_t)b * LL + s0 - 1] & 3);

#define CCHUNK(C)                                                       \
  do {                                                                  \
    const int par_ = (C) & 1;                                           \
    const float4 B0 = sF[(par_*6+0)*65 + slot];                         \
    const float4 B1 = sF[(par_*6+1)*65 + slot];                         \
    const float4 B2 = sF[(par_*6+2)*65 + slot];                         \
    const float4 B3 = sF[(par_*6+3)*65 + slot];                         \
    const float4 B4 = sF[(par_*6+4)*65 + slot];                         \
    const float4 B5 = sF[(par_*6+5)*65 + slot];                         \
    const int4   TG = sG[par_*64 + slot];                               \
    CPROC(B0,B1,B2,B3,B4,B5,TG,C);                                      \
  } while (0)

    SLOAD(0);
    SWRITE();
    __syncthreads();
    for (int qq = 0; qq < NQ; ++qq) {
        const bool more = (qq + 1 < NQ);
        if (more) SLOAD(qq + 1);          // issue early; hides under compute
        CCHUNK(2*qq);
        if (2*qq + 1 < maxnch) CCHUNK(2*qq + 1);
        if (!more) break;
        __syncthreads();                  // everyone done reading sF/sG
        SWRITE();
        __syncthreads();                  // staged data visible
    }

    if (seg0) {
        if (col == 0) {
            mats[(size_t)0*BB + p] = q0;
            mats[(size_t)1*BB + p] = q1;
            mats[(size_t)2*BB + p] = q2;
            mats[(size_t)3*BB + p] = q3;
            mexs[(size_t)0*BB + p] = mex;
        }
    } else {
        const size_t eb = ((size_t)s*16 + col*4) * BB + p;
        mats[eb + 0*BB] = q0;
        mats[eb + 1*BB] = q1;
        mats[eb + 2*BB] = q2;
        mats[eb + 3*BB] = q3;
        mexs[((size_t)s*4 + col)*BB + p] = mex;
    }
    if (col == 0) {
        if (len > s0 && len <= s0 + LSEG)   // this segment owns step len-1
            gold += sT[30 + (tags[(size_t)b * LL + len - 1] & 3)];
        golds[(size_t)s*BB + p] = gold;
    }
#undef SLOAD
#undef SWRITE
#undef CCHUNK
}

template<int S>
__global__ __launch_bounds__(256) void crf_comb(
    const float* __restrict__ mats,
    const int*   __restrict__ mexs,
    const float* __restrict__ golds,
    const float* __restrict__ trans,
    const int*   __restrict__ lens,
    const int*   __restrict__ perm,
    float* __restrict__ out)
{
    constexpr int LSEG = LL / S;
    const int tid = threadIdx.x;
    const int p   = blockIdx.x * 256 + tid;
    const int len = lens[perm[p]];

    float v0 = mats[(size_t)0*BB + p], v1 = mats[(size_t)1*BB + p];
    float v2 = mats[(size_t)2*BB + p], v3 = mats[(size_t)3*BB + p];
    int   vex  = mexs[(size_t)0*BB + p];
    float gold = golds[p];

    int lmax = len;                         // sorted => tight wave bound
    #pragma unroll
    for (int off = 32; off > 0; off >>= 1)
        lmax = max(lmax, __shfl_xor(lmax, off, 64));

    for (int s = 1; s < S; ++s) {
        if (s * LSEG >= lmax) break;
        const bool a = (s * LSEG) < len;    // only then was (s,p) written
        gold += a ? golds[(size_t)s*BB + p] : 0.f;
        float P[16]; int mc[4];
        #pragma unroll
        for (int e = 0; e < 16; ++e)
            P[e] = a ? mats[((size_t)s*16 + e)*BB + p] : 0.f;
        #pragma unroll
        for (int c = 0; c < 4; ++c)
            mc[c] = a ? mexs[((size_t)s*4 + c)*BB + p] : 0;
        const int mm = max(max(mc[0],mc[1]), max(mc[2],mc[3]));
        const float w0 = ldexpf(v0, mc[0]-mm), w1 = ldexpf(v1, mc[1]-mm);
        const float w2 = ldexpf(v2, mc[2]-mm), w3 = ldexpf(v3, mc[3]-mm);
        const float n0 = fmaf(P[0],w0, fmaf(P[4],w1, fmaf(P[8], w2, P[12]*w3)));
        const float n1 = fmaf(P[1],w0, fmaf(P[5],w1, fmaf(P[9], w2, P[13]*w3)));
        const float n2 = fmaf(P[2],w0, fmaf(P[6],w1, fmaf(P[10],w2, P[14]*w3)));
        const float n3 = fmaf(P[3],w0, fmaf(P[7],w1, fmaf(P[11],w2, P[15]*w3)));
        const float m_ = fmaxf(fmaxf(n0,n1), fmaxf(n2,n3));
        const int ee = (int)(__float_as_uint(m_) >> 23) - 127;
        if (a) {
            v0 = ldexpf(n0,-ee); v1 = ldexpf(n1,-ee);
            v2 = ldexpf(n2,-ee); v3 = ldexpf(n3,-ee);
            vex += mm + ee;
        }
    }

    const float e50=__expf(trans[30]), e51=__expf(trans[31]);
    const float e52=__expf(trans[32]), e53=__expf(trans[33]);
    const float dot = fmaf(e50,v0, fmaf(e51,v1, fmaf(e52,v2, e53*v3)));
    const float logz = fmaf((float)vex, LN2F, __logf(dot));
    float r = logz - gold;

    #pragma unroll
    for (int off = 32; off > 0; off >>= 1)
        r += __shfl_xor(r, off, 64);
    if ((tid & 63) == 0)
        atomicAdd(out, r * (1.0f / 8192.0f));
}

template<int S>
static void launch_all(const float* feats, const float* trans, const int* tags,
                       const int* lens, float* out, int out_size,
                       void* d_ws, hipStream_t stream) {
    float* mats  = (float*)d_ws;
    int*   mexs  = (int*)  (mats  + (size_t)S * 16 * BB);
    float* golds = (float*)(mexs  + (size_t)S * 4  * BB);
    int*   perm  = (int*)  (golds + (size_t)S * BB);

    k_sort<<<1, 512, 0, stream>>>(lens, perm, out, out_size);
    crf_seg<S><<<(BB/64)*S, 256, 0, stream>>>(feats, trans, tags, lens, perm,
                                              mats, mexs, golds);
    crf_comb<S><<<BB/256, 256, 0, stream>>>(mats, mexs, golds, trans, lens,
                                            perm, out);
}

extern "C" void kernel_launch(void* const* d_in, const int* in_sizes, int n_in,
                              void* d_out, int out_size, void* d_ws, size_t ws_size,
                              hipStream_t stream) {
    const float* feats = (const float*)d_in[0];
    const float* trans = (const float*)d_in[1];
    const int*   tags  = (const int*)d_in[2];
    const int*   lens  = (const int*)d_in[3];
    float* out = (float*)d_out;

    auto need = [](int S) -> size_t {
        return (size_t)S*16*BB*4 + (size_t)S*4*BB*4 + (size_t)S*BB*4
             + (size_t)BB*4;
    };
    int S = 16;
    while (S > 1 && need(S) > ws_size) S >>= 1;

    switch (S) {
      case 16: launch_all<16>(feats, trans, tags, lens, out, out_size, d_ws, stream); break;
      case 8:  launch_all<8> (feats, trans, tags, lens, out, out_size, d_ws, stream); break;
      case 4:  launch_all<4> (feats, trans, tags, lens, out, out_size, d_ws, stream); break;
      case 2:  launch_all<2> (feats, trans, tags, lens, out, out_size, d_ws, stream); break;
      default: launch_all<1> (feats, trans, tags, lens, out, out_size, d_ws, stream); break;
    }
}

// Round 5
// 41.076 us; speedup vs baseline: 1.5168x; 1.4422x over previous
//
#include <hip/hip_runtime.h>

// CRF NLL forward, B=8192, L=512, T=6 (4 real states + START/STOP).
// One wave per batch. Lane l builds the ordered product of M_l for its 8
// contiguous steps (M = diag(exp(feat)) * E, scaled-probability domain,
// power-of-2 renorm with exponent accumulated in an int). A 6-round
// __shfl_xor butterfly combines the 64 lane-products into the full 512-step
// product (operand order selected per lane by the xor bit). START boundary
// is folded into lane 0's first leaf; gold path fused per-lane and
// shuffle-reduced. Block writes one partial; a 1-block kernel reduces
// 2048 partials deterministically.

#define BB 8192
#define LL 512
#define LN2F 0.69314718055994530942f

__device__ __forceinline__ float uniformf(float x) {
    return __uint_as_float(__builtin_amdgcn_readfirstlane(__float_as_uint(x)));
}

#define RENORM16(P, MEX)                                                \
  do {                                                                  \
    float m_ = fmaxf(P[0], P[1]);                                       \
    _Pragma("unroll") for (int z_ = 2; z_ < 16; ++z_) m_ = fmaxf(m_, P[z_]); \
    const int ee_ = (int)((__float_as_uint(m_) >> 23) & 255) - 127;     \
    const float sc_ = __uint_as_float((unsigned)(127 - ee_) << 23);     \
    _Pragma("unroll") for (int z_ = 0; z_ < 16; ++z_) P[z_] *= sc_;     \
    MEX += ee_;                                                         \
  } while (0)

__global__ __launch_bounds__(256) void crf_tree(
    const float* __restrict__ feats,
    const float* __restrict__ trans,
    const int*   __restrict__ tags,
    const int*   __restrict__ lens,
    float* __restrict__ partials)
{
    __shared__ float sT[36];
    __shared__ float sW[4];

    const int tid  = threadIdx.x;
    const int lane = tid & 63;
    const int wv   = tid >> 6;
    const int b    = blockIdx.x * 4 + wv;

    if (tid < 36) sT[tid] = trans[tid];
    __syncthreads();

    // wave-uniform transition constants (SGPR via readfirstlane)
    float E[16], e4[4], e5[4];
    #pragma unroll
    for (int i = 0; i < 16; ++i)
        E[i] = uniformf(__expf(sT[(i >> 2) * 6 + (i & 3)]));
    #pragma unroll
    for (int i = 0; i < 4; ++i) {
        e4[i] = uniformf(__expf(sT[i * 6 + 4]));   // exp(trans[i][START])
        e5[i] = uniformf(__expf(sT[30 + i]));      // exp(trans[STOP][i])
    }

    const int len  = lens[b];
    const int base = lane * 8;

    // ---- load this lane's 8 steps: 48 floats (12 x float4) + 8 tags ----
    const float4* fb = (const float4*)(feats + (size_t)b * (LL * 6)) + lane * 12;
    float fl[48];
    #pragma unroll
    for (int j = 0; j < 12; ++j) {
        const float4 v = fb[j];
        fl[4*j+0] = v.x; fl[4*j+1] = v.y; fl[4*j+2] = v.z; fl[4*j+3] = v.w;
    }
    const int* tb = tags + (size_t)b * LL + base;
    const int4 ta = *(const int4*)tb;
    const int4 tb4 = *(const int4*)(tb + 4);
    int tg[8];
    tg[0]=ta.x&3;  tg[1]=ta.y&3;  tg[2]=ta.z&3;  tg[3]=ta.w&3;
    tg[4]=tb4.x&3; tg[5]=tb4.y&3; tg[6]=tb4.z&3; tg[7]=tb4.w&3;

    // boundary tag for step base-1 (lane 0 uses START=4)
    const int ptail = __shfl_up(tg[7], 1, 64);
    const int prev0 = (lane == 0) ? 4 : ptail;
    const bool lane0 = (lane == 0);

    // ---- serial leaves: P = M_{base+7} ... M_{base} (identity-extended) ----
    float P[16];
    #pragma unroll
    for (int z = 0; z < 16; ++z) P[z] = (z % 5 == 0) ? 1.f : 0.f;
    int   mex  = 0;
    float gold = 0.f;

    #pragma unroll
    for (int r = 0; r < 8; ++r) {
        const bool act = (base + r) < len;
        const float f0 = fl[6*r+0], f1 = fl[6*r+1];
        const float f2 = fl[6*r+2], f3 = fl[6*r+3];
        const float fe0 = __expf(f0), fe1 = __expf(f1);
        const float fe2 = __expf(f2), fe3 = __expf(f3);
        float T[16];
        #pragma unroll
        for (int j = 0; j < 4; ++j) {
            float t0 = fmaf(E[0], P[0*4+j], fmaf(E[1], P[1*4+j],
                       fmaf(E[2], P[2*4+j], E[3]  * P[3*4+j])));
            float t1 = fmaf(E[4], P[0*4+j], fmaf(E[5], P[1*4+j],
                       fmaf(E[6], P[2*4+j], E[7]  * P[3*4+j])));
            float t2 = fmaf(E[8], P[0*4+j], fmaf(E[9], P[1*4+j],
                       fmaf(E[10],P[2*4+j], E[11] * P[3*4+j])));
            float t3 = fmaf(E[12],P[0*4+j], fmaf(E[13],P[1*4+j],
                       fmaf(E[14],P[2*4+j], E[15] * P[3*4+j])));
            if (r == 0) {               // fold START init into lane 0's M_0
                t0 = lane0 ? e4[0] : t0;  t1 = lane0 ? e4[1] : t1;
                t2 = lane0 ? e4[2] : t2;  t3 = lane0 ? e4[3] : t3;
            }
            T[0*4+j] = t0; T[1*4+j] = t1; T[2*4+j] = t2; T[3*4+j] = t3;
        }
        #pragma unroll
        for (int j = 0; j < 4; ++j) {
            P[0*4+j] = act ? fe0 * T[0*4+j] : P[0*4+j];
            P[1*4+j] = act ? fe1 * T[1*4+j] : P[1*4+j];
            P[2*4+j] = act ? fe2 * T[2*4+j] : P[2*4+j];
            P[3*4+j] = act ? fe3 * T[3*4+j] : P[3*4+j];
        }
        // gold: trans[tag_r][tag_{r-1}] + feat_r[tag_r]
        const int tgr = tg[r];
        const int pv  = (r == 0) ? prev0 : tg[r-1];
        const float lut = sT[tgr * 6 + pv];
        const float em  = (tgr & 2) ? ((tgr & 1) ? f3 : f2)
                                    : ((tgr & 1) ? f1 : f0);
        gold += act ? (lut + em) : 0.f;
        if ((r & 3) == 3) RENORM16(P, mex);
    }

    // terminal gold: lane owning step len-1 adds trans[STOP][last_tag]
    {
        const unsigned dl = (unsigned)(len - 1 - base);
        if (dl < 8u) gold += sT[30 + (tb[dl] & 3)];
    }

    // ---- butterfly: ordered product across 64 lanes ----
    #pragma unroll
    for (int k = 1; k <= 32; k <<= 1) {
        float Q[16];
        #pragma unroll
        for (int z = 0; z < 16; ++z) Q[z] = __shfl_xor(P[z], k, 64);
        const int mq = __shfl_xor(mex, k, 64);
        const bool lat = (lane & k) != 0;      // my block is the later half
        float A[16], Bm[16];
        #pragma unroll
        for (int z = 0; z < 16; ++z) {
            A[z]  = lat ? P[z] : Q[z];         // later factor
            Bm[z] = lat ? Q[z] : P[z];         // earlier factor
        }
        float N[16];
        #pragma unroll
        for (int i = 0; i < 4; ++i)
            #pragma unroll
            for (int j = 0; j < 4; ++j)
                N[i*4+j] = fmaf(A[i*4+0], Bm[0*4+j], fmaf(A[i*4+1], Bm[1*4+j],
                           fmaf(A[i*4+2], Bm[2*4+j], A[i*4+3] * Bm[3*4+j])));
        #pragma unroll
        for (int z = 0; z < 16; ++z) P[z] = N[z];
        mex += mq;
        RENORM16(P, mex);
    }

    // gold: sum across lanes
    #pragma unroll
    for (int k = 1; k <= 32; k <<= 1)
        gold += __shfl_xor(gold, k, 64);

    // alpha = column 0 of P_total; logz = mex*ln2 + log(alpha . e5)
    const float dot = fmaf(e5[0], P[0], fmaf(e5[1], P[4],
                      fmaf(e5[2], P[8], e5[3] * P[12])));
    const float logz = fmaf((float)mex, LN2F, __logf(dot));
    const float res = logz - gold;

    if (lane == 0) sW[wv] = res;
    __syncthreads();
    if (tid == 0)
        partials[blockIdx.x] = (sW[0] + sW[1]) + (sW[2] + sW[3]);
}

__global__ __launch_bounds__(256) void k_reduce(const float* __restrict__ partials,
                                               float* __restrict__ out)
{
    __shared__ float sh[256];
    const int t = threadIdx.x;
    float s = 0.f;
    #pragma unroll
    for (int j = 0; j < 8; ++j) s += partials[t + 256 * j];
    sh[t] = s;
    __syncthreads();
    #pragma unroll
    for (int d = 128; d > 0; d >>= 1) {
        if (t < d) sh[t] += sh[t + d];
        __syncthreads();
    }
    if (t == 0) out[0] = sh[0] * (1.0f / 8192.0f);
}

extern "C" void kernel_launch(void* const* d_in, const int* in_sizes, int n_in,
                              void* d_out, int out_size, void* d_ws, size_t ws_size,
                              hipStream_t stream) {
    const float* feats = (const float*)d_in[0];
    const float* trans = (const float*)d_in[1];
    const int*   tags  = (const int*)d_in[2];
    const int*   lens  = (const int*)d_in[3];
    float* out = (float*)d_out;
    float* partials = (float*)d_ws;        // 2048 floats

    crf_tree<<<BB / 4, 256, 0, stream>>>(feats, trans, tags, lens, partials);
    k_reduce<<<1, 256, 0, stream>>>(partials, out);
}

// Round 6
// 41.050 us; speedup vs baseline: 1.5178x; 1.0006x over previous
//
#include <hip/hip_runtime.h>

// CRF NLL forward, B=8192, L=512, T=6 (4 real states + START/STOP).
// One wave per batch. Lane l builds the ordered product of M_l for its 8
// contiguous steps (M = diag(exp(feat)) * E, scaled-probability domain,
// power-of-2 renorm, exponent in an int). 5 full __shfl_xor butterfly rounds
// + 1 final mat-vec round (earlier-half operand is rank-1: all columns = alpha)
// combine the 64 lane-products into alpha over all 512 steps. Gold path fused
// per-lane and shuffle-reduced. launch_bounds(256,4) caps VGPR at 128 for
// 4 waves/SIMD; leaf feats stream in 2-step clumps to keep the live set small.

#define BB 8192
#define LL 512
#define LN2F 0.69314718055994530942f

__device__ __forceinline__ float uniformf(float x) {
    return __uint_as_float(__builtin_amdgcn_readfirstlane(__float_as_uint(x)));
}

#define RENORM16(P, MEX)                                                \
  do {                                                                  \
    float m_ = fmaxf(P[0], P[1]);                                       \
    _Pragma("unroll") for (int z_ = 2; z_ < 16; ++z_) m_ = fmaxf(m_, P[z_]); \
    const int ee_ = (int)((__float_as_uint(m_) >> 23) & 255) - 127;     \
    const float sc_ = __uint_as_float((unsigned)(127 - ee_) << 23);     \
    _Pragma("unroll") for (int z_ = 0; z_ < 16; ++z_) P[z_] *= sc_;     \
    MEX += ee_;                                                         \
  } while (0)

// One leaf step: P <- diag(exp(f)) * E * P (masked), fused gold.
#define STEP(R, F0, F1, F2, F3)                                         \
  do {                                                                  \
    const int r_ = (R);                                                 \
    const bool act_ = (base + r_) < len;                                \
    const float f0_=(F0), f1_=(F1), f2_=(F2), f3_=(F3);                 \
    const float fe0_=__expf(f0_), fe1_=__expf(f1_);                     \
    const float fe2_=__expf(f2_), fe3_=__expf(f3_);                     \
    _Pragma("unroll")                                                   \
    for (int j = 0; j < 4; ++j) {                                       \
      const float c0_=P[0*4+j], c1_=P[1*4+j], c2_=P[2*4+j], c3_=P[3*4+j]; \
      float t0_ = fmaf(E[0], c0_, fmaf(E[1], c1_, fmaf(E[2], c2_, E[3] *c3_))); \
      float t1_ = fmaf(E[4], c0_, fmaf(E[5], c1_, fmaf(E[6], c2_, E[7] *c3_))); \
      float t2_ = fmaf(E[8], c0_, fmaf(E[9], c1_, fmaf(E[10],c2_, E[11]*c3_))); \
      float t3_ = fmaf(E[12],c0_, fmaf(E[13],c1_, fmaf(E[14],c2_, E[15]*c3_))); \
      if (r_ == 0) {                      /* fold START init into lane 0 */ \
        t0_ = lane0 ? e4[0] : t0_;  t1_ = lane0 ? e4[1] : t1_;          \
        t2_ = lane0 ? e4[2] : t2_;  t3_ = lane0 ? e4[3] : t3_;          \
      }                                                                 \
      P[0*4+j] = act_ ? fe0_*t0_ : P[0*4+j];                            \
      P[1*4+j] = act_ ? fe1_*t1_ : P[1*4+j];                            \
      P[2*4+j] = act_ ? fe2_*t2_ : P[2*4+j];                            \
      P[3*4+j] = act_ ? fe3_*t3_ : P[3*4+j];                            \
    }                                                                   \
    const int tg_ = tg##R;                                              \
    const int pv_ = (r_ == 0) ? prev0 : tgp##R;                         \
    const float lut_ = sT[tg_ * 6 + pv_];                               \
    const float em_  = (tg_ & 2) ? ((tg_ & 1) ? f3_ : f2_)              \
                                 : ((tg_ & 1) ? f1_ : f0_);             \
    gold += act_ ? (lut_ + em_) : 0.f;                                  \
  } while (0)

__global__ __launch_bounds__(256, 4) void crf_tree(
    const float* __restrict__ feats,
    const float* __restrict__ trans,
    const int*   __restrict__ tags,
    const int*   __restrict__ lens,
    float* __restrict__ partials)
{
    __shared__ float sT[36];

    const int tid  = threadIdx.x;
    const int lane = tid & 63;
    const int wv   = tid >> 6;
    const int b    = blockIdx.x * 4 + wv;

    if (tid < 36) sT[tid] = trans[tid];
    __syncthreads();

    // wave-uniform transition constants (SGPR via readfirstlane)
    float E[16], e4[4], e5[4];
    #pragma unroll
    for (int i = 0; i < 16; ++i)
        E[i] = uniformf(__expf(sT[(i >> 2) * 6 + (i & 3)]));
    #pragma unroll
    for (int i = 0; i < 4; ++i) {
        e4[i] = uniformf(__expf(sT[i * 6 + 4]));   // exp(trans[i][START])
        e5[i] = uniformf(__expf(sT[30 + i]));      // exp(trans[STOP][i])
    }

    const int len  = lens[b];
    const int base = lane * 8;
    const bool lane0 = (lane == 0);

    const float4* fb = (const float4*)(feats + (size_t)b * (LL * 6)) + lane * 12;
    const int* tbp = tags + (size_t)b * LL + base;
    const int4 ta  = *(const int4*)tbp;
    const int4 tb4 = *(const int4*)(tbp + 4);
    const int tg0=ta.x&3,  tg1=ta.y&3,  tg2=ta.z&3,  tg3=ta.w&3;
    const int tg4=tb4.x&3, tg5=tb4.y&3, tg6=tb4.z&3, tg7=tb4.w&3;
    const int ptail = __shfl_up(tg7, 1, 64);
    const int prev0 = lane0 ? 4 : ptail;
    const int tgp0=0, tgp1=tg0, tgp2=tg1, tgp3=tg2,
              tgp4=tg3, tgp5=tg4, tgp6=tg5, tgp7=tg6;   // prev-tag per step

    float P[16];
    #pragma unroll
    for (int z = 0; z < 16; ++z) P[z] = (z % 5 == 0) ? 1.f : 0.f;
    int   mex  = 0;
    float gold = 0.f;

    // ---- leaves: stream 2 steps (3 float4) at a time ----
    {
        const float4 v0 = fb[0], v1 = fb[1], v2 = fb[2];
        STEP(0, v0.x, v0.y, v0.z, v0.w);
        STEP(1, v1.z, v1.w, v2.x, v2.y);
    }
    {
        const float4 v0 = fb[3], v1 = fb[4], v2 = fb[5];
        STEP(2, v0.x, v0.y, v0.z, v0.w);
        STEP(3, v1.z, v1.w, v2.x, v2.y);
    }
    RENORM16(P, mex);
    {
        const float4 v0 = fb[6], v1 = fb[7], v2 = fb[8];
        STEP(4, v0.x, v0.y, v0.z, v0.w);
        STEP(5, v1.z, v1.w, v2.x, v2.y);
    }
    {
        const float4 v0 = fb[9], v1 = fb[10], v2 = fb[11];
        STEP(6, v0.x, v0.y, v0.z, v0.w);
        STEP(7, v1.z, v1.w, v2.x, v2.y);
    }
    RENORM16(P, mex);

    // terminal gold: lane owning step len-1 adds trans[STOP][last_tag]
    {
        const unsigned dl = (unsigned)(len - 1 - base);
        if (dl < 8u) gold += sT[30 + (tbp[dl] & 3)];
    }

    // ---- butterfly rounds k=1..16 (full 4x4 products) ----
    #pragma unroll
    for (int k = 1; k <= 16; k <<= 1) {
        float Q[16];
        #pragma unroll
        for (int z = 0; z < 16; ++z) Q[z] = __shfl_xor(P[z], k, 64);
        const int mq = __shfl_xor(mex, k, 64);
        const bool lat = (lane & k) != 0;
        float A[16], Bm[16];
        #pragma unroll
        for (int z = 0; z < 16; ++z) {
            A[z]  = lat ? P[z] : Q[z];         // later factor
            Bm[z] = lat ? Q[z] : P[z];         // earlier factor
        }
        #pragma unroll
        for (int i = 0; i < 4; ++i)
            #pragma unroll
            for (int j = 0; j < 4; ++j)
                P[i*4+j] = fmaf(A[i*4+0], Bm[0*4+j], fmaf(A[i*4+1], Bm[1*4+j],
                           fmaf(A[i*4+2], Bm[2*4+j], A[i*4+3] * Bm[3*4+j])));
        mex += mq;
        RENORM16(P, mex);
    }

    // ---- final round k=32: earlier half is rank-1 -> mat-vec only ----
    float al0, al1, al2, al3;
    {
        float Q[16];
        #pragma unroll
        for (int z = 0; z < 16; ++z) Q[z] = __shfl_xor(P[z], 32, 64);
        const int mq = __shfl_xor(mex, 32, 64);
        const bool lat = (lane & 32) != 0;
        const float b0 = lat ? Q[0]  : P[0];    // earlier factor, column 0
        const float b1 = lat ? Q[4]  : P[4];
        const float b2 = lat ? Q[8]  : P[8];
        const float b3 = lat ? Q[12] : P[12];
        #pragma unroll
        for (int i = 0; i < 4; ++i) {
            const float a0 = lat ? P[i*4+0] : Q[i*4+0];
            const float a1 = lat ? P[i*4+1] : Q[i*4+1];
            const float a2 = lat ? P[i*4+2] : Q[i*4+2];
            const float a3 = lat ? P[i*4+3] : Q[i*4+3];
            const float v = fmaf(a0, b0, fmaf(a1, b1, fmaf(a2, b2, a3 * b3)));
            if (i == 0) al0 = v; else if (i == 1) al1 = v;
            else if (i == 2) al2 = v; else al3 = v;
        }
        mex += mq;
    }

    // gold: sum across lanes
    #pragma unroll
    for (int k = 1; k <= 32; k <<= 1)
        gold += __shfl_xor(gold, k, 64);

    const float dot = fmaf(e5[0], al0, fmaf(e5[1], al1,
                      fmaf(e5[2], al2, e5[3] * al3)));
    const float logz = fmaf((float)mex, LN2F, __logf(dot));
    if (lane == 0)
        partials[b] = logz - gold;
}

__global__ __launch_bounds__(256) void k_reduce(const float* __restrict__ partials,
                                               float* __restrict__ out)
{
    __shared__ float sh[256];
    const int t = threadIdx.x;
    float s = 0.f;
    #pragma unroll
    for (int j = 0; j < 32; ++j) s += partials[t + 256 * j];
    sh[t] = s;
    __syncthreads();
    #pragma unroll
    for (int d = 128; d > 0; d >>= 1) {
        if (t < d) sh[t] += sh[t + d];
        __syncthreads();
    }
    if (t == 0) out[0] = sh[0] * (1.0f / 8192.0f);
}

extern "C" void kernel_launch(void* const* d_in, const int* in_sizes, int n_in,
                              void* d_out, int out_size, void* d_ws, size_t ws_size,
                              hipStream_t stream) {
    const float* feats = (const float*)d_in[0];
    const float* trans = (const float*)d_in[1];
    const int*   tags  = (const int*)d_in[2];
    const int*   lens  = (const int*)d_in[3];
    float* out = (float*)d_out;
    float* partials = (float*)d_ws;        // 8192 floats

    crf_tree<<<BB / 4, 256, 0, stream>>>(feats, trans, tags, lens, partials);
    k_reduce<<<1, 256, 0, stream>>>(partials, out);
}

// Round 7
// 40.820 us; speedup vs baseline: 1.5263x; 1.0056x over previous
//
#include <hip/hip_runtime.h>

// CRF NLL forward, B=8192, L=512, T=6 (4 real states + START/STOP).
// One wave per batch. Wave cooperatively stages its batch's 12 KB of feats
// into LDS with fully-coalesced global loads (lane i <- chunk i), then lane l
// reads steps 8l..8l+7 from LDS and builds the ordered product of
// M = diag(exp(feat)) * E (scaled-probability domain, power-of-2 renorm,
// exponent in an int). 5 full __shfl_xor butterfly rounds + 1 final mat-vec
// round (earlier half is rank-1: columns = alpha) produce alpha over all 512
// steps. Gold path fused per-lane and shuffle-reduced. Partial per batch;
// 1-block k_reduce sums deterministically.

#define BB 8192
#define LL 512
#define LN2F 0.69314718055994530942f

__device__ __forceinline__ float uniformf(float x) {
    return __uint_as_float(__builtin_amdgcn_readfirstlane(__float_as_uint(x)));
}

#define RENORM16(P, MEX)                                                \
  do {                                                                  \
    float m_ = fmaxf(P[0], P[1]);                                       \
    _Pragma("unroll") for (int z_ = 2; z_ < 16; ++z_) m_ = fmaxf(m_, P[z_]); \
    const int ee_ = (int)((__float_as_uint(m_) >> 23) & 255) - 127;     \
    const float sc_ = __uint_as_float((unsigned)(127 - ee_) << 23);     \
    _Pragma("unroll") for (int z_ = 0; z_ < 16; ++z_) P[z_] *= sc_;     \
    MEX += ee_;                                                         \
  } while (0)

// One leaf step: P <- diag(exp(f)) * E * P (masked), fused gold.
#define STEP(R, F0, F1, F2, F3)                                         \
  do {                                                                  \
    const int r_ = (R);                                                 \
    const bool act_ = (base + r_) < len;                                \
    const float f0_=(F0), f1_=(F1), f2_=(F2), f3_=(F3);                 \
    const float fe0_=__expf(f0_), fe1_=__expf(f1_);                     \
    const float fe2_=__expf(f2_), fe3_=__expf(f3_);                     \
    _Pragma("unroll")                                                   \
    for (int j = 0; j < 4; ++j) {                                       \
      const float c0_=P[0*4+j], c1_=P[1*4+j], c2_=P[2*4+j], c3_=P[3*4+j]; \
      float t0_ = fmaf(E[0], c0_, fmaf(E[1], c1_, fmaf(E[2], c2_, E[3] *c3_))); \
      float t1_ = fmaf(E[4], c0_, fmaf(E[5], c1_, fmaf(E[6], c2_, E[7] *c3_))); \
      float t2_ = fmaf(E[8], c0_, fmaf(E[9], c1_, fmaf(E[10],c2_, E[11]*c3_))); \
      float t3_ = fmaf(E[12],c0_, fmaf(E[13],c1_, fmaf(E[14],c2_, E[15]*c3_))); \
      if (r_ == 0) {                      /* fold START init into lane 0 */ \
        t0_ = lane0 ? e4[0] : t0_;  t1_ = lane0 ? e4[1] : t1_;          \
        t2_ = lane0 ? e4[2] : t2_;  t3_ = lane0 ? e4[3] : t3_;          \
      }                                                                 \
      P[0*4+j] = act_ ? fe0_*t0_ : P[0*4+j];                            \
      P[1*4+j] = act_ ? fe1_*t1_ : P[1*4+j];                            \
      P[2*4+j] = act_ ? fe2_*t2_ : P[2*4+j];                            \
      P[3*4+j] = act_ ? fe3_*t3_ : P[3*4+j];                            \
    }                                                                   \
    const int tg_ = tg##R;                                              \
    const int pv_ = (r_ == 0) ? prev0 : tgp##R;                         \
    const float lut_ = sT[tg_ * 6 + pv_];                               \
    const float em_  = (tg_ & 2) ? ((tg_ & 1) ? f3_ : f2_)              \
                                 : ((tg_ & 1) ? f1_ : f0_);             \
    gold += act_ ? (lut_ + em_) : 0.f;                                  \
  } while (0)

__global__ __launch_bounds__(256, 3) void crf_tree(
    const float* __restrict__ feats,
    const float* __restrict__ trans,
    const int*   __restrict__ tags,
    const int*   __restrict__ lens,
    float* __restrict__ partials)
{
    __shared__ float4 sF[4 * 832];   // per wave: 64 lanes x 13 float4 (pad 12->13)
    __shared__ float  sT[36];

    const int tid  = threadIdx.x;
    const int lane = tid & 63;
    const int wv   = tid >> 6;
    const int b    = blockIdx.x * 4 + wv;

    if (tid < 36) sT[tid] = trans[tid];
    __syncthreads();

    // ---- wave-cooperative coalesced staging: 12 KB feats -> LDS ----
    // global chunk c = j*64 + lane (coalesced); belongs to compute-lane c/12,
    // piece c%12; padded dest (c/12)*13 + c%12.
    const float4* fb4 = (const float4*)(feats + (size_t)b * (LL * 6));
    float4* sFw = &sF[wv * 832];
    {
        float4 stg[12];
        #pragma unroll
        for (int j = 0; j < 12; ++j)
            stg[j] = fb4[j * 64 + lane];
        #pragma unroll
        for (int j = 0; j < 12; ++j) {
            const int c = j * 64 + lane;
            const int L = c / 12;
            const int pcs = c - L * 12;
            sFw[L * 13 + pcs] = stg[j];
        }
    }

    // wave-uniform transition constants (SGPR via readfirstlane)
    float E[16], e4[4], e5[4];
    #pragma unroll
    for (int i = 0; i < 16; ++i)
        E[i] = uniformf(__expf(sT[(i >> 2) * 6 + (i & 3)]));
    #pragma unroll
    for (int i = 0; i < 4; ++i) {
        e4[i] = uniformf(__expf(sT[i * 6 + 4]));   // exp(trans[i][START])
        e5[i] = uniformf(__expf(sT[30 + i]));      // exp(trans[STOP][i])
    }

    const int len  = lens[b];
    const int base = lane * 8;
    const bool lane0 = (lane == 0);

    const float4* fl4 = &sFw[lane * 13];           // this lane's 12 float4s

    const int* tbp = tags + (size_t)b * LL + base;
    const int4 ta  = *(const int4*)tbp;
    const int4 tb4 = *(const int4*)(tbp + 4);
    const int tg0=ta.x&3,  tg1=ta.y&3,  tg2=ta.z&3,  tg3=ta.w&3;
    const int tg4=tb4.x&3, tg5=tb4.y&3, tg6=tb4.z&3, tg7=tb4.w&3;
    const int ptail = __shfl_up(tg7, 1, 64);
    const int prev0 = lane0 ? 4 : ptail;
    const int tgp0=0, tgp1=tg0, tgp2=tg1, tgp3=tg2,
              tgp4=tg3, tgp5=tg4, tgp6=tg5, tgp7=tg6;   // prev-tag per step

    float P[16];
    #pragma unroll
    for (int z = 0; z < 16; ++z) P[z] = (z % 5 == 0) ? 1.f : 0.f;
    int   mex  = 0;
    float gold = 0.f;

    // ---- leaves: 2 steps (3 float4 from LDS) at a time ----
    {
        const float4 v0 = fl4[0], v1 = fl4[1], v2 = fl4[2];
        STEP(0, v0.x, v0.y, v0.z, v0.w);
        STEP(1, v1.z, v1.w, v2.x, v2.y);
    }
    {
        const float4 v0 = fl4[3], v1 = fl4[4], v2 = fl4[5];
        STEP(2, v0.x, v0.y, v0.z, v0.w);
        STEP(3, v1.z, v1.w, v2.x, v2.y);
    }
    RENORM16(P, mex);
    {
        const float4 v0 = fl4[6], v1 = fl4[7], v2 = fl4[8];
        STEP(4, v0.x, v0.y, v0.z, v0.w);
        STEP(5, v1.z, v1.w, v2.x, v2.y);
    }
    {
        const float4 v0 = fl4[9], v1 = fl4[10], v2 = fl4[11];
        STEP(6, v0.x, v0.y, v0.z, v0.w);
        STEP(7, v1.z, v1.w, v2.x, v2.y);
    }
    RENORM16(P, mex);

    // terminal gold: lane owning step len-1 adds trans[STOP][last_tag]
    {
        const unsigned dl = (unsigned)(len - 1 - base);
        if (dl < 8u) gold += sT[30 + (tbp[dl] & 3)];
    }

    // ---- butterfly rounds k=1..16 (full 4x4 products) ----
    #pragma unroll
    for (int k = 1; k <= 16; k <<= 1) {
        float Q[16];
        #pragma unroll
        for (int z = 0; z < 16; ++z) Q[z] = __shfl_xor(P[z], k, 64);
        const int mq = __shfl_xor(mex, k, 64);
        const bool lat = (lane & k) != 0;
        float A[16], Bm[16];
        #pragma unroll
        for (int z = 0; z < 16; ++z) {
            A[z]  = lat ? P[z] : Q[z];         // later factor
            Bm[z] = lat ? Q[z] : P[z];         // earlier factor
        }
        #pragma unroll
        for (int i = 0; i < 4; ++i)
            #pragma unroll
            for (int j = 0; j < 4; ++j)
                P[i*4+j] = fmaf(A[i*4+0], Bm[0*4+j], fmaf(A[i*4+1], Bm[1*4+j],
                           fmaf(A[i*4+2], Bm[2*4+j], A[i*4+3] * Bm[3*4+j])));
        mex += mq;
        RENORM16(P, mex);
    }

    // ---- final round k=32: earlier half is rank-1 -> mat-vec only ----
    float al0, al1, al2, al3;
    {
        float Q[16];
        #pragma unroll
        for (int z = 0; z < 16; ++z) Q[z] = __shfl_xor(P[z], 32, 64);
        const int mq = __shfl_xor(mex, 32, 64);
        const bool lat = (lane & 32) != 0;
        const float b0 = lat ? Q[0]  : P[0];    // earlier factor, column 0
        const float b1 = lat ? Q[4]  : P[4];
        const float b2 = lat ? Q[8]  : P[8];
        const float b3 = lat ? Q[12] : P[12];
        #pragma unroll
        for (int i = 0; i < 4; ++i) {
            const float a0 = lat ? P[i*4+0] : Q[i*4+0];
            const float a1 = lat ? P[i*4+1] : Q[i*4+1];
            const float a2 = lat ? P[i*4+2] : Q[i*4+2];
            const float a3 = lat ? P[i*4+3] : Q[i*4+3];
            const float v = fmaf(a0, b0, fmaf(a1, b1, fmaf(a2, b2, a3 * b3)));
            if (i == 0) al0 = v; else if (i == 1) al1 = v;
            else if (i == 2) al2 = v; else al3 = v;
        }
        mex += mq;
    }

    // gold: sum across lanes
    #pragma unroll
    for (int k = 1; k <= 32; k <<= 1)
        gold += __shfl_xor(gold, k, 64);

    const float dot = fmaf(e5[0], al0, fmaf(e5[1], al1,
                      fmaf(e5[2], al2, e5[3] * al3)));
    const float logz = fmaf((float)mex, LN2F, __logf(dot));
    if (lane == 0)
        partials[b] = logz - gold;
}

__global__ __launch_bounds__(256) void k_reduce(const float* __restrict__ partials,
                                               float* __restrict__ out)
{
    __shared__ float sh[256];
    const int t = threadIdx.x;
    float s = 0.f;
    #pragma unroll
    for (int j = 0; j < 32; ++j) s += partials[t + 256 * j];
    sh[t] = s;
    __syncthreads();
    #pragma unroll
    for (int d = 128; d > 0; d >>= 1) {
        if (t < d) sh[t] += sh[t + d];
        __syncthreads();
    }
    if (t == 0) out[0] = sh[0] * (1.0f / 8192.0f);
}

extern "C" void kernel_launch(void* const* d_in, const int* in_sizes, int n_in,
                              void* d_out, int out_size, void* d_ws, size_t ws_size,
                              hipStream_t stream) {
    const float* feats = (const float*)d_in[0];
    const float* trans = (const float*)d_in[1];
    const int*   tags  = (const int*)d_in[2];
    const int*   lens  = (const int*)d_in[3];
    float* out = (float*)d_out;
    float* partials = (float*)d_ws;        // 8192 floats

    crf_tree<<<BB / 4, 256, 0, stream>>>(feats, trans, tags, lens, partials);
    k_reduce<<<1, 256, 0, stream>>>(partials, out);
}

// Round 8
// 39.284 us; speedup vs baseline: 1.5860x; 1.0391x over previous
//
#include <hip/hip_runtime.h>

// CRF NLL forward, B=8192, L=512, T=6 (4 real states + START/STOP).
// One wave per batch. Lane l builds the ordered product of M_l for its 8
// contiguous steps (M = diag(exp(feat)) * E, scaled-probability domain,
// power-of-2 renorm, exponent in an int). 5 full __shfl_xor butterfly rounds
// + 1 final mat-vec round (earlier half is rank-1) produce alpha over all
// 512 steps. Gold fused per-lane and shuffle-reduced.
// This revision: loads ONLY the 4 used emission columns (dwordx4+2x dwordx2
// per 2 steps: 128B/lane instead of 192B), issues all loads up front, and
// specializes step 0 (P=I -> 16 muls instead of 64 FMAs).

#define BB 8192
#define LL 512
#define LN2F 0.69314718055994530942f

__device__ __forceinline__ float uniformf(float x) {
    return __uint_as_float(__builtin_amdgcn_readfirstlane(__float_as_uint(x)));
}

#define RENORM16(P, MEX)                                                \
  do {                                                                  \
    float m_ = fmaxf(P[0], P[1]);                                       \
    _Pragma("unroll") for (int z_ = 2; z_ < 16; ++z_) m_ = fmaxf(m_, P[z_]); \
    const int ee_ = (int)((__float_as_uint(m_) >> 23) & 255) - 127;     \
    const float sc_ = __uint_as_float((unsigned)(127 - ee_) << 23);     \
    _Pragma("unroll") for (int z_ = 0; z_ < 16; ++z_) P[z_] *= sc_;     \
    MEX += ee_;                                                         \
  } while (0)

// One leaf step for r>=1: P <- diag(exp(f)) * E * P (masked), fused gold.
#define STEP(R, F0, F1, F2, F3)                                         \
  do {                                                                  \
    const bool act_ = (base + (R)) < len;                               \
    const float f0_=(F0), f1_=(F1), f2_=(F2), f3_=(F3);                 \
    const float fe0_=__expf(f0_), fe1_=__expf(f1_);                     \
    const float fe2_=__expf(f2_), fe3_=__expf(f3_);                     \
    _Pragma("unroll")                                                   \
    for (int j = 0; j < 4; ++j) {                                       \
      const float c0_=P[0*4+j], c1_=P[1*4+j], c2_=P[2*4+j], c3_=P[3*4+j]; \
      const float t0_ = fmaf(E[0], c0_, fmaf(E[1], c1_, fmaf(E[2], c2_, E[3] *c3_))); \
      const float t1_ = fmaf(E[4], c0_, fmaf(E[5], c1_, fmaf(E[6], c2_, E[7] *c3_))); \
      const float t2_ = fmaf(E[8], c0_, fmaf(E[9], c1_, fmaf(E[10],c2_, E[11]*c3_))); \
      const float t3_ = fmaf(E[12],c0_, fmaf(E[13],c1_, fmaf(E[14],c2_, E[15]*c3_))); \
      P[0*4+j] = act_ ? fe0_*t0_ : P[0*4+j];                            \
      P[1*4+j] = act_ ? fe1_*t1_ : P[1*4+j];                            \
      P[2*4+j] = act_ ? fe2_*t2_ : P[2*4+j];                            \
      P[3*4+j] = act_ ? fe3_*t3_ : P[3*4+j];                            \
    }                                                                   \
    const int tg_ = tg##R;                                              \
    const float lut_ = sT[tg_ * 6 + tgp##R];                            \
    const float em_  = (tg_ & 2) ? ((tg_ & 1) ? f3_ : f2_)              \
                                 : ((tg_ & 1) ? f1_ : f0_);             \
    gold += act_ ? (lut_ + em_) : 0.f;                                  \
  } while (0)

__global__ __launch_bounds__(256, 4) void crf_tree(
    const float* __restrict__ feats,
    const float* __restrict__ trans,
    const int*   __restrict__ tags,
    const int*   __restrict__ lens,
    float* __restrict__ partials)
{
    __shared__ float sT[36];

    const int tid  = threadIdx.x;
    const int lane = tid & 63;
    const int wv   = tid >> 6;
    const int b    = blockIdx.x * 4 + wv;

    if (tid < 36) sT[tid] = trans[tid];
    __syncthreads();

    // wave-uniform transition constants (SGPR via readfirstlane)
    float E[16], e4[4], e5[4];
    #pragma unroll
    for (int i = 0; i < 16; ++i)
        E[i] = uniformf(__expf(sT[(i >> 2) * 6 + (i & 3)]));
    #pragma unroll
    for (int i = 0; i < 4; ++i) {
        e4[i] = uniformf(__expf(sT[i * 6 + 4]));   // exp(trans[i][START])
        e5[i] = uniformf(__expf(sT[30 + i]));      // exp(trans[STOP][i])
    }

    const int len  = lens[b];
    const int base = lane * 8;
    const bool lane0 = (lane == 0);

    // ---- issue ALL loads up front: 4 used columns only (32B per 2 steps) ----
    const float* fp = feats + (size_t)b * (LL * 6) + lane * 48;
    const float4 A0 = *(const float4*)(fp + 0);    // step 0: f0..f3
    const float2 A1 = *(const float2*)(fp + 6);    // step 1: f0,f1
    const float2 A2 = *(const float2*)(fp + 8);    // step 1: f2,f3
    const float4 B0 = *(const float4*)(fp + 12);   // step 2
    const float2 B1 = *(const float2*)(fp + 18);   // step 3
    const float2 B2 = *(const float2*)(fp + 20);
    const float4 C0 = *(const float4*)(fp + 24);   // step 4
    const float2 C1 = *(const float2*)(fp + 30);   // step 5
    const float2 C2 = *(const float2*)(fp + 32);
    const float4 D0 = *(const float4*)(fp + 36);   // step 6
    const float2 D1 = *(const float2*)(fp + 42);   // step 7
    const float2 D2 = *(const float2*)(fp + 44);

    const int* tbp = tags + (size_t)b * LL + base;
    const int4 ta  = *(const int4*)tbp;
    const int4 tb4 = *(const int4*)(tbp + 4);
    const int tg0=ta.x&3,  tg1=ta.y&3,  tg2=ta.z&3,  tg3=ta.w&3;
    const int tg4=tb4.x&3, tg5=tb4.y&3, tg6=tb4.z&3, tg7=tb4.w&3;
    const int ptail = __shfl_up(tg7, 1, 64);
    const int prev0 = lane0 ? 4 : ptail;
    const int tgp1=tg0, tgp2=tg1, tgp3=tg2,
              tgp4=tg3, tgp5=tg4, tgp6=tg5, tgp7=tg6;   // prev-tag per step

    float P[16];
    #pragma unroll
    for (int z = 0; z < 16; ++z) P[z] = (z % 5 == 0) ? 1.f : 0.f;
    int   mex  = 0;
    float gold = 0.f;

    // ---- step 0 specialized: P = diag(fe) * (lane0 ? e4-cols : E) ----
    {
        const bool act_ = base < len;
        const float f0_=A0.x, f1_=A0.y, f2_=A0.z, f3_=A0.w;
        const float fe0_=__expf(f0_), fe1_=__expf(f1_);
        const float fe2_=__expf(f2_), fe3_=__expf(f3_);
        #pragma unroll
        for (int j = 0; j < 4; ++j) {
            const float t0_ = lane0 ? e4[0] : E[0*4+j];
            const float t1_ = lane0 ? e4[1] : E[1*4+j];
            const float t2_ = lane0 ? e4[2] : E[2*4+j];
            const float t3_ = lane0 ? e4[3] : E[3*4+j];
            P[0*4+j] = act_ ? fe0_*t0_ : P[0*4+j];
            P[1*4+j] = act_ ? fe1_*t1_ : P[1*4+j];
            P[2*4+j] = act_ ? fe2_*t2_ : P[2*4+j];
            P[3*4+j] = act_ ? fe3_*t3_ : P[3*4+j];
        }
        const float lut_ = sT[tg0 * 6 + prev0];
        const float em_  = (tg0 & 2) ? ((tg0 & 1) ? f3_ : f2_)
                                     : ((tg0 & 1) ? f1_ : f0_);
        gold += act_ ? (lut_ + em_) : 0.f;
    }
    STEP(1, A1.x, A1.y, A2.x, A2.y);
    STEP(2, B0.x, B0.y, B0.z, B0.w);
    STEP(3, B1.x, B1.y, B2.x, B2.y);
    RENORM16(P, mex);
    STEP(4, C0.x, C0.y, C0.z, C0.w);
    STEP(5, C1.x, C1.y, C2.x, C2.y);
    STEP(6, D0.x, D0.y, D0.z, D0.w);
    STEP(7, D1.x, D1.y, D2.x, D2.y);
    RENORM16(P, mex);

    // terminal gold: lane owning step len-1 adds trans[STOP][last_tag]
    {
        const unsigned dl = (unsigned)(len - 1 - base);
        if (dl < 8u) gold += sT[30 + (tbp[dl] & 3)];
    }

    // ---- butterfly rounds k=1..16 (full 4x4 products) ----
    #pragma unroll
    for (int k = 1; k <= 16; k <<= 1) {
        float Q[16];
        #pragma unroll
        for (int z = 0; z < 16; ++z) Q[z] = __shfl_xor(P[z], k, 64);
        const int mq = __shfl_xor(mex, k, 64);
        const bool lat = (lane & k) != 0;
        float A[16], Bm[16];
        #pragma unroll
        for (int z = 0; z < 16; ++z) {
            A[z]  = lat ? P[z] : Q[z];         // later factor
            Bm[z] = lat ? Q[z] : P[z];         // earlier factor
        }
        #pragma unroll
        for (int i = 0; i < 4; ++i)
            #pragma unroll
            for (int j = 0; j < 4; ++j)
                P[i*4+j] = fmaf(A[i*4+0], Bm[0*4+j], fmaf(A[i*4+1], Bm[1*4+j],
                           fmaf(A[i*4+2], Bm[2*4+j], A[i*4+3] * Bm[3*4+j])));
        mex += mq;
        RENORM16(P, mex);
    }

    // ---- final round k=32: earlier half is rank-1 -> mat-vec only ----
    float al0, al1, al2, al3;
    {
        float Q[16];
        #pragma unroll
        for (int z = 0; z < 16; ++z) Q[z] = __shfl_xor(P[z], 32, 64);
        const int mq = __shfl_xor(mex, 32, 64);
        const bool lat = (lane & 32) != 0;
        const float b0 = lat ? Q[0]  : P[0];    // earlier factor, column 0
        const float b1 = lat ? Q[4]  : P[4];
        const float b2 = lat ? Q[8]  : P[8];
        const float b3 = lat ? Q[12] : P[12];
        #pragma unroll
        for (int i = 0; i < 4; ++i) {
            const float a0 = lat ? P[i*4+0] : Q[i*4+0];
            const float a1 = lat ? P[i*4+1] : Q[i*4+1];
            const float a2 = lat ? P[i*4+2] : Q[i*4+2];
            const float a3 = lat ? P[i*4+3] : Q[i*4+3];
            const float v = fmaf(a0, b0, fmaf(a1, b1, fmaf(a2, b2, a3 * b3)));
            if (i == 0) al0 = v; else if (i == 1) al1 = v;
            else if (i == 2) al2 = v; else al3 = v;
        }
        mex += mq;
    }

    // gold: sum across lanes
    #pragma unroll
    for (int k = 1; k <= 32; k <<= 1)
        gold += __shfl_xor(gold, k, 64);

    const float dot = fmaf(e5[0], al0, fmaf(e5[1], al1,
                      fmaf(e5[2], al2, e5[3] * al3)));
    const float logz = fmaf((float)mex, LN2F, __logf(dot));
    if (lane == 0)
        partials[b] = logz - gold;
}

__global__ __launch_bounds__(256) void k_reduce(const float* __restrict__ partials,
                                               float* __restrict__ out)
{
    __shared__ float sh[256];
    const int t = threadIdx.x;
    float s = 0.f;
    #pragma unroll
    for (int j = 0; j < 32; ++j) s += partials[t + 256 * j];
    sh[t] = s;
    __syncthreads();
    #pragma unroll
    for (int d = 128; d > 0; d >>= 1) {
        if (t < d) sh[t] += sh[t + d];
        __syncthreads();
    }
    if (t == 0) out[0] = sh[0] * (1.0f / 8192.0f);
}

extern "C" void kernel_launch(void* const* d_in, const int* in_sizes, int n_in,
                              void* d_out, int out_size, void* d_ws, size_t ws_size,
                              hipStream_t stream) {
    const float* feats = (const float*)d_in[0];
    const float* trans = (const float*)d_in[1];
    const int*   tags  = (const int*)d_in[2];
    const int*   lens  = (const int*)d_in[3];
    float* out = (float*)d_out;
    float* partials = (float*)d_ws;        // 8192 floats

    crf_tree<<<BB / 4, 256, 0, stream>>>(feats, trans, tags, lens, partials);
    k_reduce<<<1, 256, 0, stream>>>(partials, out);
}